// Round 3
// baseline (177.338 us; speedup 1.0000x reference)
//
#include <hip/hip_runtime.h>
#include <hip/hip_bf16.h>

// SparseGCM: 2-layer causal-window GCN on MI355X — split-bf16 MFMA version.
// Edges are j->i for j in [i-16,i) per batch, weights normalize to 1.0 ->
// "gather+segment_sum" == 16-wide sliding-window sum over time. Only output
// rows i in [512,640) matter: layer1 computes i in [496,640).
//
// Precision: single-bf16 failed (absmax 0.163): L1 errors are temporally
// correlated (windows overlap 15/16) so the L2 window-sum amplifies them x16.
// Fix: split each value v = hi + lo (bf16 pair, residual 2^-17) and compute
// A@W ~= Ahi@Whi + Alo@Whi + Ahi@Wlo  (3 MFMAs, near-fp32 accuracy).

namespace {

constexpr int BQ    = 64;
constexpr int FEATC = 256;
constexpr int M1 = 144;   // layer-1 rows per batch: i in [496,640)
constexpr int M2 = 128;   // layer-2 rows per batch: i in [512,640)

using short8 = __attribute__((ext_vector_type(8))) short;   // 8 bf16 = 4 VGPR
using f32x4  = __attribute__((ext_vector_type(4))) float;

__device__ inline unsigned short f2bf(float f) {  // round-to-nearest-even
  union { float f; unsigned u; } v{f};
  unsigned r = v.u + 0x7FFFu + ((v.u >> 16) & 1u);
  return (unsigned short)(r >> 16);
}
__device__ inline float bf2f(unsigned short h) {
  union { unsigned u; float f; } v{(unsigned)h << 16};
  return v.f;
}
__device__ inline void split2(float v, unsigned short& hi, unsigned short& lo) {
  hi = f2bf(v);
  lo = f2bf(v - bf2f(hi));
}

// ---------------------------------------------------------------------------
// Weight prep: Wt{hi,lo}[n][k] = split(W[k][n]); z picks {W1s,W1n,W2s,W2n};
// z&1 selects k-offset 0/256 of Wt1/Wt2 ([256 n][512 k] each).
// ---------------------------------------------------------------------------
__global__ __launch_bounds__(256) void wprep_kernel(
    const float* __restrict__ W1s, const float* __restrict__ W1n,
    const float* __restrict__ W2s, const float* __restrict__ W2n,
    unsigned short* __restrict__ Wt1hi, unsigned short* __restrict__ Wt1lo,
    unsigned short* __restrict__ Wt2hi, unsigned short* __restrict__ Wt2lo) {
  __shared__ float tile[64][65];
  const int z = blockIdx.z;
  const float* src = (z == 0) ? W1s : (z == 1) ? W1n : (z == 2) ? W2s : W2n;
  unsigned short* dhi = (z < 2) ? Wt1hi : Wt2hi;
  unsigned short* dlo = (z < 2) ? Wt1lo : Wt2lo;
  const int koff = (z & 1) * 256;
  const int k0 = blockIdx.x * 64, n0 = blockIdx.y * 64;
  const int c = threadIdx.x & 63, r4 = threadIdx.x >> 6;
  #pragma unroll
  for (int p = 0; p < 16; ++p) {
    const int k = r4 + p * 4;
    tile[k][c] = src[(size_t)(k0 + k) * FEATC + n0 + c];   // coalesced read
  }
  __syncthreads();
  #pragma unroll
  for (int p = 0; p < 16; ++p) {
    const int n = r4 + p * 4;
    unsigned short hi, lo;
    split2(tile[c][n], hi, lo);
    dhi[(size_t)(n0 + n) * 512 + koff + k0 + c] = hi;      // coalesced write
    dlo[(size_t)(n0 + n) * 512 + koff + k0 + c] = lo;
  }
}

// ---------------------------------------------------------------------------
// prep1: row t (i=496+t) per batch:
//   s1{hi,lo}[b*144+t][f] = split(row i)          (nodes if i<512 else x)
//   w1{hi,lo}[b*144+t][f] = split(sum rows [i-16,i))
// ---------------------------------------------------------------------------
__global__ __launch_bounds__(256) void prep1_kernel(
    const float* __restrict__ x, const float* __restrict__ nodes,
    unsigned short* __restrict__ s1hi, unsigned short* __restrict__ s1lo,
    unsigned short* __restrict__ w1hi, unsigned short* __restrict__ w1lo) {
  const int b = blockIdx.x;
  const int f = threadIdx.x;
  const float* nb = nodes + ((size_t)b * 640) * FEATC + f;
  const float* xb = x     + ((size_t)b * 128) * FEATC + f;
  const size_t base = ((size_t)b * M1) * FEATC + f;

  auto val = [&](int i) -> float {
    return (i < 512) ? nb[(size_t)i * FEATC] : xb[(size_t)(i - 512) * FEATC];
  };
  float win = 0.f;
  #pragma unroll
  for (int i = 480; i < 496; ++i) win += val(i);
  for (int t = 0; t < M1; ++t) {
    const float v = val(496 + t);
    unsigned short hi, lo;
    split2(v, hi, lo);
    s1hi[base + (size_t)t * FEATC] = hi;
    s1lo[base + (size_t)t * FEATC] = lo;
    split2(win, hi, lo);
    w1hi[base + (size_t)t * FEATC] = hi;
    w1lo[base + (size_t)t * FEATC] = lo;
    win += v - val(480 + t);
  }
}

// ---------------------------------------------------------------------------
// prep2: h1 rows j (i=496+j). Output t (i=512+t): window = h1 rows [t,t+16).
//   w2{hi,lo}[b*128+t][f] = split(sum)
// (self half of L2 reads h1{hi,lo} directly with row remap +16)
// ---------------------------------------------------------------------------
__global__ __launch_bounds__(256) void prep2_kernel(
    const unsigned short* __restrict__ h1hi, const unsigned short* __restrict__ h1lo,
    unsigned short* __restrict__ w2hi, unsigned short* __restrict__ w2lo) {
  const int b = blockIdx.x;
  const int f = threadIdx.x;
  const size_t hb = ((size_t)b * M1) * FEATC + f;
  const size_t ob = ((size_t)b * M2) * FEATC + f;

  auto hval = [&](int j) -> float {
    return bf2f(h1hi[hb + (size_t)j * FEATC]) + bf2f(h1lo[hb + (size_t)j * FEATC]);
  };
  float win = 0.f;
  #pragma unroll
  for (int j = 0; j < 16; ++j) win += hval(j);
  for (int t = 0; t < M2; ++t) {
    unsigned short hi, lo;
    split2(win, hi, lo);
    w2hi[ob + (size_t)t * FEATC] = hi;
    w2lo[ob + (size_t)t * FEATC] = lo;
    win += hval(16 + t) - hval(t);
  }
}

// ---------------------------------------------------------------------------
// Split-bf16 MFMA GEMM + bias + tanh over K=512 (k<256: self, else window):
//   C[m][n] = tanh(sum_k A[m][k]*Wt[n][k] + bias[n])
// A halves are [.][256] hi/lo pairs; self rows remapped r->(r/rpb)*bpb+r%rpb+off.
// Wt: [256 n][512 k] hi/lo. Tile 64x64, 4 waves (wave = 16 N-cols x 64 M-rows).
// mfma_f32_16x16x32_bf16 fragments: A row=lane&15, k=(lane>>4)*8+e (16B slice);
// B col=lane&15 same k; D col=lane&15, row=(lane>>4)*4+r.
// ---------------------------------------------------------------------------
template <bool OUT_SPLIT>
__global__ __launch_bounds__(256) void gemm_tanh_mfma(
    const unsigned short* __restrict__ Ashi, const unsigned short* __restrict__ Aslo,
    const unsigned short* __restrict__ Awhi, const unsigned short* __restrict__ Awlo,
    const unsigned short* __restrict__ Bhi,  const unsigned short* __restrict__ Blo,
    const float* __restrict__ bias,
    float* __restrict__ Cf, unsigned short* __restrict__ Chi,
    unsigned short* __restrict__ Clo,
    int rpb, int bpb, int offs) {
  const int t    = threadIdx.x;
  const int wave = t >> 6;
  const int lane = t & 63;
  const int lr = lane & 15, kg = lane >> 4;
  const int m0 = blockIdx.x * 64;
  const int n0 = blockIdx.y * 64 + wave * 16;
  const int kbase = kg * 8;

  int offS[4], offW[4];
  #pragma unroll
  for (int mt = 0; mt < 4; ++mt) {
    const int rA = m0 + mt * 16 + lr;
    const int rs = (rA / rpb) * bpb + (rA % rpb) + offs;
    offS[mt] = rs * FEATC + kbase;
    offW[mt] = rA * FEATC + kbase;
  }

  const unsigned short* bphi = Bhi + (size_t)(n0 + lr) * 512 + kbase;
  const unsigned short* bplo = Blo + (size_t)(n0 + lr) * 512 + kbase;

  f32x4 acc[4] = {};
  #pragma unroll
  for (int ks = 0; ks < 16; ++ks) {
    const int k0 = ks * 32;
    const short8 bhi = *(const short8*)(bphi + k0);
    const short8 blo = *(const short8*)(bplo + k0);
    const bool self = (k0 < 256);
    const unsigned short* ahiB = self ? Ashi : Awhi;
    const unsigned short* aloB = self ? Aslo : Awlo;
    const int kk = self ? k0 : (k0 - 256);
    #pragma unroll
    for (int mt = 0; mt < 4; ++mt) {
      const int ro = (self ? offS[mt] : offW[mt]) + kk;
      const short8 ahi = *(const short8*)(ahiB + ro);
      const short8 alo = *(const short8*)(aloB + ro);
      acc[mt] = __builtin_amdgcn_mfma_f32_16x16x32_bf16(ahi, bhi, acc[mt], 0, 0, 0);
      acc[mt] = __builtin_amdgcn_mfma_f32_16x16x32_bf16(alo, bhi, acc[mt], 0, 0, 0);
      acc[mt] = __builtin_amdgcn_mfma_f32_16x16x32_bf16(ahi, blo, acc[mt], 0, 0, 0);
    }
  }

  const int col = n0 + lr;
  const float bv = bias[col];
  #pragma unroll
  for (int mt = 0; mt < 4; ++mt) {
    #pragma unroll
    for (int r = 0; r < 4; ++r) {
      const size_t idx = (size_t)(m0 + mt * 16 + kg * 4 + r) * FEATC + col;
      const float v = tanhf(acc[mt][r] + bv);
      if constexpr (OUT_SPLIT) {
        unsigned short hi, lo;
        split2(v, hi, lo);
        Chi[idx] = hi;
        Clo[idx] = lo;
      } else {
        Cf[idx] = v;
      }
    }
  }
}

}  // namespace

extern "C" void kernel_launch(void* const* d_in, const int* in_sizes, int n_in,
                              void* d_out, int out_size, void* d_ws, size_t ws_size,
                              hipStream_t stream) {
  const float* x     = (const float*)d_in[0];
  const float* nodes = (const float*)d_in[1];
  // d_in[2] = edge_weight: forward value is ew/ew == 1.0 -> unused.
  const float* W1s = (const float*)d_in[3];
  const float* W1n = (const float*)d_in[4];
  const float* b1  = (const float*)d_in[5];
  const float* W2s = (const float*)d_in[6];
  const float* W2n = (const float*)d_in[7];
  const float* b2  = (const float*)d_in[8];
  float* out = (float*)d_out;

  // workspace layout (ushort elems) — total 37,748,736 B (fits: round-1 used same)
  const size_t m1_sz = (size_t)BQ * M1 * FEATC;   // 2,359,296
  const size_t m2_sz = (size_t)BQ * M2 * FEATC;   // 2,097,152
  const size_t wt_sz = (size_t)256 * 512;         // 131,072
  const size_t need = (6 * m1_sz + 2 * m2_sz + 4 * wt_sz) * sizeof(unsigned short);
  if (ws_size < need) return;

  unsigned short* p = (unsigned short*)d_ws;
  unsigned short* s1hi = p; p += m1_sz;
  unsigned short* s1lo = p; p += m1_sz;
  unsigned short* w1hi = p; p += m1_sz;
  unsigned short* w1lo = p; p += m1_sz;
  unsigned short* h1hi = p; p += m1_sz;
  unsigned short* h1lo = p; p += m1_sz;
  unsigned short* w2hi = p; p += m2_sz;
  unsigned short* w2lo = p; p += m2_sz;
  unsigned short* Wt1hi = p; p += wt_sz;
  unsigned short* Wt1lo = p; p += wt_sz;
  unsigned short* Wt2hi = p; p += wt_sz;
  unsigned short* Wt2lo = p; p += wt_sz;

  wprep_kernel<<<dim3(4, 4, 4), 256, 0, stream>>>(W1s, W1n, W2s, W2n,
                                                  Wt1hi, Wt1lo, Wt2hi, Wt2lo);
  prep1_kernel<<<BQ, 256, 0, stream>>>(x, nodes, s1hi, s1lo, w1hi, w1lo);
  gemm_tanh_mfma<true><<<dim3((BQ * M1) / 64, FEATC / 64), 256, 0, stream>>>(
      s1hi, s1lo, w1hi, w1lo, Wt1hi, Wt1lo, b1, nullptr, h1hi, h1lo,
      M1, M1, 0);
  prep2_kernel<<<BQ, 256, 0, stream>>>(h1hi, h1lo, w2hi, w2lo);
  gemm_tanh_mfma<false><<<dim3((BQ * M2) / 64, FEATC / 64), 256, 0, stream>>>(
      h1hi, h1lo, w2hi, w2lo, Wt2hi, Wt2lo, b2, out, nullptr, nullptr,
      M2, M1, 16);
}

// Round 5
// 61.206 us; speedup vs baseline: 2.8974x; 2.8974x over previous
//
#include <hip/hip_runtime.h>
#include <hip/hip_bf16.h>

// SparseGCM: 2-layer causal-window GCN on MI355X — split-bf16, LDS-staged MFMA.
// Edges are j->i for j in [i-16,i) per batch, weights normalize to 1.0 ->
// "gather+segment_sum" == 16-wide sliding-window sum. Only outputs i in
// [512,640) matter: layer1 computes i in [496,640).
//
// Precision: single-bf16 fails (temporally correlated L1 errors are amplified
// x16 by the L2 window sum). Split v = hi + lo (bf16 pair); need
// hi*w_hi + lo*w_hi + hi*w_lo. R4 bug: concat-K pairing gave hi*hi + lo*lo
// (cross terms absent) -> single-bf16 error. Fix: A=[s_hi|s_lo|win_hi|win_lo]
// (K=1024), W1=[ws_hi|wn_hi], W2=[ws_lo|wn_lo] (K=512 each); per double-tile
// stage {A_hi, A_lo, W1, W2} and issue A_hi*W1 + A_hi*W2 + A_lo*W1.
//
// GEMM: 64x64 tiles, 4 waves, double-buffered LDS via global_load_lds(16B)
// with pre-swizzled source + XOR-swizzled ds_read_b128 (byte ^= (row&7)<<4).

namespace {

constexpr int BQ    = 64;
constexpr int FEATC = 256;
constexpr int M1 = 144;   // layer-1 rows/batch: i in [496,640)
constexpr int M2 = 128;   // layer-2 rows/batch: i in [512,640)
constexpr int KK = 1024;  // A packed K
constexpr int KW = 512;   // W packed K

using ushort = unsigned short;
using short8 = __attribute__((ext_vector_type(8))) short;   // 8 bf16
using f32x4  = __attribute__((ext_vector_type(4))) float;

__device__ __forceinline__ ushort f2bf(float f) {  // RNE
  union { float f; unsigned u; } v{f};
  unsigned r = v.u + 0x7FFFu + ((v.u >> 16) & 1u);
  return (ushort)(r >> 16);
}
__device__ __forceinline__ float bf2f(ushort h) {
  union { unsigned u; float f; } v{(unsigned)h << 16};
  return v.f;
}
__device__ __forceinline__ void split2(float v, ushort& hi, ushort& lo) {
  hi = f2bf(v);
  lo = f2bf(v - bf2f(hi));
}
__device__ __forceinline__ void gl_lds16(const void* g, void* lds) {
  __builtin_amdgcn_global_load_lds(
      (const __attribute__((address_space(1))) void*)g,
      (__attribute__((address_space(3))) void*)lds, 16, 0, 0);
}

// ---------------------------------------------------------------------------
// wprep: transpose W[k][n] -> W1[n][512]=[ws_hi|wn_hi], W2[n][512]=[ws_lo|wn_lo]
// z in {0..3} = {W1s, W1n, W2s, W2n}; zsel=z&1 picks self(0)/nbr(1) segment.
// ---------------------------------------------------------------------------
__global__ __launch_bounds__(256) void wprep_kernel(
    const float* __restrict__ W1s, const float* __restrict__ W1n,
    const float* __restrict__ W2s, const float* __restrict__ W2n,
    ushort* __restrict__ W1_1, ushort* __restrict__ W2_1,
    ushort* __restrict__ W1_2, ushort* __restrict__ W2_2) {
  __shared__ float tile[64][65];
  const int z = blockIdx.z;
  const float* src = (z == 0) ? W1s : (z == 1) ? W1n : (z == 2) ? W2s : W2n;
  ushort* dstH = (z < 2) ? W1_1 : W1_2;
  ushort* dstL = (z < 2) ? W2_1 : W2_2;
  const int koff = (z & 1) * 256;
  const int k0 = blockIdx.x * 64, n0 = blockIdx.y * 64;
  const int c = threadIdx.x & 63, r4 = threadIdx.x >> 6;
  #pragma unroll
  for (int p = 0; p < 16; ++p) {
    const int k = r4 + p * 4;
    tile[k][c] = src[(size_t)(k0 + k) * FEATC + n0 + c];
  }
  __syncthreads();
  #pragma unroll
  for (int p = 0; p < 16; ++p) {
    const int n = r4 + p * 4;
    ushort hi, lo;
    split2(tile[c][n], hi, lo);
    dstH[(size_t)(n0 + n) * KW + koff + k0 + c] = hi;
    dstL[(size_t)(n0 + n) * KW + koff + k0 + c] = lo;
  }
}

// ---------------------------------------------------------------------------
// prep1: Acat1[b*144+t][1024] for t-chunk of 16. Row i = 496+t.
//   [f]=s_hi [256+f]=s_lo [512+f]=win_hi [768+f]=win_lo
// ---------------------------------------------------------------------------
__global__ __launch_bounds__(256) void prep1_kernel(
    const float* __restrict__ x, const float* __restrict__ nodes,
    ushort* __restrict__ Acat1) {
  const int b = blockIdx.x, c = blockIdx.y, f = threadIdx.x;
  const int t0 = c * 16, i0 = 496 + t0;
  const float* nb = nodes + ((size_t)b * 640) * FEATC + f;
  const float* xb = x     + ((size_t)b * 128) * FEATC + f;

  float v[32];
  #pragma unroll
  for (int d = 0; d < 32; ++d) {
    const int i = i0 - 16 + d;
    v[d] = (i < 512) ? nb[(size_t)i * FEATC] : xb[(size_t)(i - 512) * FEATC];
  }
  float win = 0.f;
  #pragma unroll
  for (int d = 0; d < 16; ++d) win += v[d];

  ushort* ao = Acat1 + ((size_t)(b * M1 + t0)) * KK + f;
  #pragma unroll
  for (int tt = 0; tt < 16; ++tt) {
    ushort hi, lo;
    split2(v[16 + tt], hi, lo);
    ao[(size_t)tt * KK]       = hi;
    ao[(size_t)tt * KK + 256] = lo;
    split2(win, hi, lo);
    ao[(size_t)tt * KK + 512] = hi;
    ao[(size_t)tt * KK + 768] = lo;
    win += v[16 + tt] - v[tt];
  }
}

// ---------------------------------------------------------------------------
// prep2: fill window segments of Acat2 (self segs written by gemm1 epilogue).
// h1 row j (i=496+j): j<16 in h1head{hi,lo}[b*16+j][f]; j>=16 in Acat2 row
// b*128+(j-16) at [f](hi)/[256+f](lo). Output t: window = h1 rows [t,t+16).
// ---------------------------------------------------------------------------
__global__ __launch_bounds__(256) void prep2_kernel(
    const ushort* __restrict__ h1hhi, const ushort* __restrict__ h1hlo,
    ushort* __restrict__ Acat2) {
  const int b = blockIdx.x, c = blockIdx.y, f = threadIdx.x;
  const int t0 = c * 16;

  float hv[32];
  #pragma unroll
  for (int d = 0; d < 32; ++d) {
    const int j = t0 + d;
    if (j < 16) {
      const size_t o = (size_t)(b * 16 + j) * FEATC + f;
      hv[d] = bf2f(h1hhi[o]) + bf2f(h1hlo[o]);
    } else {
      const size_t o = (size_t)(b * M2 + (j - 16)) * KK + f;
      hv[d] = bf2f(Acat2[o]) + bf2f(Acat2[o + 256]);
    }
  }
  float win = 0.f;
  #pragma unroll
  for (int d = 0; d < 16; ++d) win += hv[d];

  ushort* ao = Acat2 + ((size_t)(b * M2 + t0)) * KK + f;
  #pragma unroll
  for (int tt = 0; tt < 16; ++tt) {
    ushort hi, lo;
    split2(win, hi, lo);
    ao[(size_t)tt * KK + 512] = hi;
    ao[(size_t)tt * KK + 768] = lo;
    win += hv[16 + tt] - hv[tt];
  }
}

// ---------------------------------------------------------------------------
// Split-bf16 LDS-staged MFMA GEMM + bias + tanh.
// Per iteration tt (8 double-k-tiles): A hi tile (col Ahi*64), A lo tile
// (col (Ahi+4)*64), W1 tile (col tt*64), W2 tile (col tt*64); MFMAs:
// A_hi*W1 + A_hi*W2 + A_lo*W1.  Ahi = tt<4 ? tt : tt+4.
// MODE 0: split C -> Acat2 self segs (j>=16) / h1head (j<16). MODE 1: fp32 C.
// ---------------------------------------------------------------------------
template <int MODE>
__global__ __launch_bounds__(256, 2) void gemm_mfma(
    const ushort* __restrict__ A, const ushort* __restrict__ W1,
    const ushort* __restrict__ W2, const float* __restrict__ bias,
    ushort* __restrict__ Acat2, ushort* __restrict__ h1hhi,
    ushort* __restrict__ h1hlo, float* __restrict__ out) {
  __shared__ __align__(16) unsigned char AhiB[2][8192];  // [64 rows][128B]
  __shared__ __align__(16) unsigned char AloB[2][8192];
  __shared__ __align__(16) unsigned char B1B[2][8192];
  __shared__ __align__(16) unsigned char B2B[2][8192];

  const int t = threadIdx.x;
  const int wave = t >> 6, lane = t & 63;
  const int wm = wave >> 1, wn = wave & 1;
  const int lr = lane & 15, kg = lane >> 4;
  const int m0 = blockIdx.x * 64;
  const int n0 = blockIdx.y * 64;

  // staging: instr (wave,i) covers LDS rows (wave*2+i)*8..+8; lane l writes
  // LDS row base+(l>>3), byte col (l&7)*16 <- global byte col ((l&7)^(l>>3))*16
  const int rowl = lane >> 3;
  const int scol = ((lane & 7) ^ rowl) << 4;        // pre-swizzled byte col
  const ushort* aSrc[2];
  const ushort* b1Src[2];
  const ushort* b2Src[2];
  int ldsoff[2];
  #pragma unroll
  for (int i = 0; i < 2; ++i) {
    const int r = (wave * 2 + i) * 8 + rowl;        // 0..63
    aSrc[i]  = A  + (size_t)(m0 + r) * KK + (scol >> 1);
    b1Src[i] = W1 + (size_t)(n0 + r) * KW + (scol >> 1);
    b2Src[i] = W2 + (size_t)(n0 + r) * KW + (scol >> 1);
    ldsoff[i] = (wave * 2 + i) * 1024;
  }

  // ds_read byte offsets (XOR swizzle on read side, same involution)
  int aoff[2][2], boff[2][2];                       // [tile][ks]
  #pragma unroll
  for (int mt = 0; mt < 2; ++mt)
    #pragma unroll
    for (int ks = 0; ks < 2; ++ks) {
      const int ar = wm * 32 + mt * 16 + lr;
      const int br = wn * 32 + mt * 16 + lr;
      const int col = ks * 64 + kg * 16;
      aoff[mt][ks] = ar * 128 + (col ^ ((ar & 7) << 4));
      boff[mt][ks] = br * 128 + (col ^ ((br & 7) << 4));
    }

  auto stage = [&](int q, int tt) {
    const int ah = (tt < 4) ? tt : tt + 4;          // A hi tile index
    #pragma unroll
    for (int i = 0; i < 2; ++i) {
      gl_lds16(aSrc[i]  + ah * 64,       &AhiB[q][ldsoff[i]]);
      gl_lds16(aSrc[i]  + (ah + 4) * 64, &AloB[q][ldsoff[i]]);
      gl_lds16(b1Src[i] + tt * 64,       &B1B[q][ldsoff[i]]);
      gl_lds16(b2Src[i] + tt * 64,       &B2B[q][ldsoff[i]]);
    }
  };

  f32x4 acc[2][2] = {};
  stage(0, 0);

  #pragma unroll
  for (int tt = 0; tt < 8; ++tt) {
    const int bf = tt & 1;
    __syncthreads();                   // drains vmcnt (stage into bf) + lgkm
    if (tt < 7) stage(bf ^ 1, tt + 1);

    short8 ah[2][2], al[2][2], b1f[2][2], b2f[2][2];
    #pragma unroll
    for (int mt = 0; mt < 2; ++mt)
      #pragma unroll
      for (int ks = 0; ks < 2; ++ks) {
        ah[mt][ks]  = *(const short8*)(&AhiB[bf][aoff[mt][ks]]);
        al[mt][ks]  = *(const short8*)(&AloB[bf][aoff[mt][ks]]);
        b1f[mt][ks] = *(const short8*)(&B1B[bf][boff[mt][ks]]);
        b2f[mt][ks] = *(const short8*)(&B2B[bf][boff[mt][ks]]);
      }
    #pragma unroll
    for (int ks = 0; ks < 2; ++ks)
      #pragma unroll
      for (int mt = 0; mt < 2; ++mt)
        #pragma unroll
        for (int nt = 0; nt < 2; ++nt) {
          acc[mt][nt] = __builtin_amdgcn_mfma_f32_16x16x32_bf16(
              ah[mt][ks], b1f[nt][ks], acc[mt][nt], 0, 0, 0);
          acc[mt][nt] = __builtin_amdgcn_mfma_f32_16x16x32_bf16(
              ah[mt][ks], b2f[nt][ks], acc[mt][nt], 0, 0, 0);
          acc[mt][nt] = __builtin_amdgcn_mfma_f32_16x16x32_bf16(
              al[mt][ks], b1f[nt][ks], acc[mt][nt], 0, 0, 0);
        }
  }

  // epilogue: bias + tanh
  float bv[2];
  #pragma unroll
  for (int nt = 0; nt < 2; ++nt) bv[nt] = bias[n0 + wn * 32 + nt * 16 + lr];

  #pragma unroll
  for (int mt = 0; mt < 2; ++mt)
    #pragma unroll
    for (int nt = 0; nt < 2; ++nt)
      #pragma unroll
      for (int r = 0; r < 4; ++r) {
        const int row = m0 + wm * 32 + mt * 16 + kg * 4 + r;
        const int col = n0 + wn * 32 + nt * 16 + lr;
        const float vv = tanhf(acc[mt][nt][r] + bv[nt]);
        if constexpr (MODE == 0) {
          const int b = row / M1, j = row % M1;     // row = b*144 + j
          ushort hi, lo;
          split2(vv, hi, lo);
          if (j >= 16) {
            const size_t o = (size_t)(b * M2 + (j - 16)) * KK + col;
            Acat2[o]       = hi;
            Acat2[o + 256] = lo;
          } else {
            const size_t o = (size_t)(b * 16 + j) * FEATC + col;
            h1hhi[o] = hi;
            h1hlo[o] = lo;
          }
        } else {
          out[(size_t)row * FEATC + col] = vv;
        }
      }
}

}  // namespace

extern "C" void kernel_launch(void* const* d_in, const int* in_sizes, int n_in,
                              void* d_out, int out_size, void* d_ws, size_t ws_size,
                              hipStream_t stream) {
  const float* x     = (const float*)d_in[0];
  const float* nodes = (const float*)d_in[1];
  // d_in[2] = edge_weight: forward value ew/ew == 1.0 -> unused.
  const float* W1s = (const float*)d_in[3];
  const float* W1n = (const float*)d_in[4];
  const float* b1  = (const float*)d_in[5];
  const float* W2s = (const float*)d_in[6];
  const float* W2n = (const float*)d_in[7];
  const float* b2  = (const float*)d_in[8];
  float* out = (float*)d_out;

  // workspace (ushort elems) — 37,748,736 B total (== R4 footprint, fits)
  const size_t acat1_sz = (size_t)BQ * M1 * KK;      // 9,437,184
  const size_t acat2_sz = (size_t)BQ * M2 * KK;      // 8,388,608
  const size_t head_sz  = (size_t)BQ * 16 * FEATC;   // 262,144
  const size_t w_sz     = (size_t)FEATC * KW;        // 131,072
  const size_t need = (acat1_sz + acat2_sz + 2 * head_sz + 4 * w_sz) * sizeof(ushort);
  if (ws_size < need) return;

  ushort* p = (ushort*)d_ws;
  ushort* Acat1 = p; p += acat1_sz;
  ushort* Acat2 = p; p += acat2_sz;
  ushort* h1hhi = p; p += head_sz;
  ushort* h1hlo = p; p += head_sz;
  ushort* W1_1  = p; p += w_sz;
  ushort* W2_1  = p; p += w_sz;
  ushort* W1_2  = p; p += w_sz;
  ushort* W2_2  = p; p += w_sz;

  wprep_kernel<<<dim3(4, 4, 4), 256, 0, stream>>>(W1s, W1n, W2s, W2n,
                                                  W1_1, W2_1, W1_2, W2_2);
  prep1_kernel<<<dim3(BQ, 9), 256, 0, stream>>>(x, nodes, Acat1);
  gemm_mfma<0><<<dim3((BQ * M1) / 64, FEATC / 64), 256, 0, stream>>>(
      Acat1, W1_1, W2_1, b1, Acat2, h1hhi, h1hlo, nullptr);
  prep2_kernel<<<dim3(BQ, 8), 256, 0, stream>>>(h1hhi, h1hlo, Acat2);
  gemm_mfma<1><<<dim3((BQ * M2) / 64, FEATC / 64), 256, 0, stream>>>(
      Acat2, W1_2, W2_2, b2, nullptr, nullptr, nullptr, out);
}